// Round 4
// baseline (146.368 us; speedup 1.0000x reference)
//
#include <hip/hip_runtime.h>

#define NTHREADS 256
#define NBLOCKS 1344              // 5376 tiles / 1344 = 4 tiles per block (exact)
#define TILE_F4 768               // per stream: 256 threads x 3 float4
#define TILE_FLOATS 3072          // 12 KB per stream, 24 KB LDS total
#define TILE_TRIPLES 1024

__device__ __forceinline__ float wave_reduce(float v) {
    #pragma unroll
    for (int off = 32; off > 0; off >>= 1) v += __shfl_down(v, off, 64);
    return v;
}

__device__ __forceinline__ float block_reduce(float v) {
    v = wave_reduce(v);
    __shared__ float smem[NTHREADS / 64];
    const int lane = threadIdx.x & 63;
    const int wave = threadIdx.x >> 6;
    if (lane == 0) smem[wave] = v;
    __syncthreads();
    float s = 0.f;
    if (threadIdx.x == 0) {
        #pragma unroll
        for (int w = 0; w < NTHREADS / 64; ++w) s += smem[w];
    }
    return s;
}

// Stage via global_load_lds DMA (bypasses the VGPR round-trip / L1 vector-load
// path, which R1-R3 evidence suggests caps pure reads at ~3.1 TB/s chip-wide).
__global__ __launch_bounds__(NTHREADS) void dis_partial_kernel(
    const float4* __restrict__ p4, const float4* __restrict__ t4,
    const float* __restrict__ pred, const float* __restrict__ targ,
    float* __restrict__ partials, int ntile, int ntrip) {
    __shared__ float lp[TILE_FLOATS];
    __shared__ float lt[TILE_FLOATS];
    const int t = threadIdx.x;
    const int wave = t >> 6;      // wave-uniform
    const int lane = t & 63;
    float acc = 0.f;

    for (int tile = blockIdx.x; tile < ntile; tile += gridDim.x) {
        const float4* gp = p4 + tile * TILE_F4;
        const float4* gt = t4 + tile * TILE_F4;
        // 3 DMA issues per wave per stream; LDS dest = wave-uniform base,
        // HW scatters lane i at base + i*16 — contiguous, matching layout.
        #pragma unroll
        for (int j = 0; j < 3; ++j) {
            const int slot = j * NTHREADS + wave * 64;   // wave-uniform f4 slot
            __builtin_amdgcn_global_load_lds(
                (const __attribute__((address_space(1))) void*)(gp + slot + lane),
                (__attribute__((address_space(3))) void*)(&lp[slot * 4]),
                16, 0, 0);
            __builtin_amdgcn_global_load_lds(
                (const __attribute__((address_space(1))) void*)(gt + slot + lane),
                (__attribute__((address_space(3))) void*)(&lt[slot * 4]),
                16, 0, 0);
        }
        __builtin_amdgcn_s_waitcnt(0x0f70);  // vmcnt(0)
        __syncthreads();
        #pragma unroll
        for (int j = 0; j < 4; ++j) {
            const int tr = j * NTHREADS + t;
            const float dx = lp[3 * tr + 0] - lt[3 * tr + 0];
            const float dy = lp[3 * tr + 1] - lt[3 * tr + 1];
            const float dz = lp[3 * tr + 2] - lt[3 * tr + 2];
            acc += sqrtf(dx * dx + dy * dy + dz * dz);
        }
        __syncthreads();
    }

    // Generic scalar tail (empty for B=262144: 5376 tiles exactly).
    for (int j = ntile * TILE_TRIPLES + blockIdx.x * NTHREADS + t; j < ntrip;
         j += gridDim.x * NTHREADS) {
        const float dx = pred[3 * j + 0] - targ[3 * j + 0];
        const float dy = pred[3 * j + 1] - targ[3 * j + 1];
        const float dz = pred[3 * j + 2] - targ[3 * j + 2];
        acc += sqrtf(dx * dx + dy * dy + dz * dz);
    }

    const float s = block_reduce(acc);
    if (threadIdx.x == 0) partials[blockIdx.x] = s;
}

__global__ __launch_bounds__(NTHREADS) void dis_finalize_kernel(
    const float* __restrict__ partials, float* __restrict__ out,
    int nblocks, float scale) {
    float acc = 0.f;
    for (int i = threadIdx.x; i < nblocks; i += NTHREADS) acc += partials[i];
    const float s = block_reduce(acc);
    if (threadIdx.x == 0) out[0] = s * scale;  // full overwrite of poisoned d_out
}

extern "C" void kernel_launch(void* const* d_in, const int* in_sizes, int n_in,
                              void* d_out, int out_size, void* d_ws, size_t ws_size,
                              hipStream_t stream) {
    const float* pred = (const float*)d_in[0];
    const float* targ = (const float*)d_in[1];
    float* out = (float*)d_out;
    float* partials = (float*)d_ws;  // one float per block, each block owns its slot

    const int n = in_sizes[0];              // B * 63 = 16,515,072
    const int ntrip = n / 3;                // 5,505,024 joint distances
    const int ntile = n / TILE_FLOATS;      // 5376 full tiles (exact here)
    const float scale = 1.0f / (float)ntrip;

    dis_partial_kernel<<<NBLOCKS, NTHREADS, 0, stream>>>(
        (const float4*)pred, (const float4*)targ, pred, targ, partials,
        ntile, ntrip);
    dis_finalize_kernel<<<1, NTHREADS, 0, stream>>>(partials, out, NBLOCKS, scale);
}